// Round 2
// baseline (1078.721 us; speedup 1.0000x reference)
//
#include <hip/hip_runtime.h>
#include <hip/hip_bf16.h>
#include <cstdint>

// Problem constants (B,N,D,H,DH,M) = (4,4096,512,8,64,128)
#define BN_TOT   16384     // B*N
#define NSEQ     4096
#define NBATCH   4
#define DMODEL   512
#define NH       8
#define DHD      64
#define MPROJ    128
#define TWOM     256

__device__ __forceinline__ float4 ldg4(const float* p) {
    return *reinterpret_cast<const float4*>(p);
}

// ---------------------------------------------------------------------------
// K1: fused  value/pos_proj/slope_proj GEMMs (per-head 64x64 tile, K=512)
//     + scale/offset, row norms, Fourier features (sin/cos) -> q', k'
// grid = (NH, BN/64), block = 256
// ---------------------------------------------------------------------------
__global__ __launch_bounds__(256, 2)
void k1_proj_ff(const float* __restrict__ src, const float* __restrict__ pos,
                const float* __restrict__ slo, const float* __restrict__ vw,
                const float* __restrict__ pw, const float* __restrict__ scale,
                const float* __restrict__ offs, const float* __restrict__ proj,
                float* __restrict__ value, float* __restrict__ norms,
                float* __restrict__ qprime, float* __restrict__ kprime)
{
    // LDS union:
    //   main loop: As_t[3][32][68] at 0,2176,4352 ; Bs[2][32][68] at 6528,8704
    //   epilogue : qp[64][68] at 0 ; kp[64][68] at 4352 ; proj[128][68] at 8704
    __shared__ float lds[17408];   // 69632 B
    const int tid = threadIdx.x;
    const int h    = blockIdx.x;
    const int row0 = blockIdx.y * 64;     // global row = b*N+n
    const int tx = tid & 15, ty = tid >> 4;

    float accv[4][4] = {{0.f}}, accp[4][4] = {{0.f}}, accs[4][4] = {{0.f}};

    for (int k0 = 0; k0 < DMODEL; k0 += 32) {
        __syncthreads();
        // A tiles (src,pos,slo), stored transposed As_t[m][kk][r]
        #pragma unroll
        for (int li = 0; li < 6; ++li) {
            int i = li * 256 + tid;            // 0..1535
            int m = i >> 9;
            int rem = i & 511;
            int r = rem >> 3;                  // 0..63
            int cq = rem & 7;                  // k chunk
            const float* A = (m == 0) ? src : (m == 1) ? pos : slo;
            float4 v = ldg4(&A[(size_t)(row0 + r) * DMODEL + k0 + cq * 4]);
            float* base = &lds[m * 2176 + cq * 4 * 68 + r];
            base[0] = v.x; base[68] = v.y; base[136] = v.z; base[204] = v.w;
        }
        // B tiles (value_weight, pos_ft_weight), Bs[w][kk][c]
        #pragma unroll
        for (int li = 0; li < 4; ++li) {
            int i = li * 256 + tid;            // 0..1023
            int w = i >> 9;
            int rem = i & 511;
            int kk = rem >> 4;                 // 0..31
            int cq = rem & 15;                 // c chunk
            const float* W = w ? pw : vw;
            float4 v = ldg4(&W[(size_t)(k0 + kk) * DMODEL + h * DHD + cq * 4]);
            *reinterpret_cast<float4*>(&lds[6528 + w * 2176 + kk * 68 + cq * 4]) = v;
        }
        __syncthreads();
        #pragma unroll 8
        for (int kk = 0; kk < 32; ++kk) {
            float4 a0 = *reinterpret_cast<const float4*>(&lds[       kk * 68 + ty * 4]);
            float4 a1 = *reinterpret_cast<const float4*>(&lds[2176 + kk * 68 + ty * 4]);
            float4 a2 = *reinterpret_cast<const float4*>(&lds[4352 + kk * 68 + ty * 4]);
            float4 b0 = *reinterpret_cast<const float4*>(&lds[6528 + kk * 68 + tx * 4]);
            float4 b1 = *reinterpret_cast<const float4*>(&lds[8704 + kk * 68 + tx * 4]);
            float a0a[4] = {a0.x, a0.y, a0.z, a0.w};
            float a1a[4] = {a1.x, a1.y, a1.z, a1.w};
            float a2a[4] = {a2.x, a2.y, a2.z, a2.w};
            float b0a[4] = {b0.x, b0.y, b0.z, b0.w};
            float b1a[4] = {b1.x, b1.y, b1.z, b1.w};
            #pragma unroll
            for (int i = 0; i < 4; ++i)
                #pragma unroll
                for (int j = 0; j < 4; ++j) {
                    accv[i][j] = fmaf(a0a[i], b0a[j], accv[i][j]);
                    accp[i][j] = fmaf(a1a[i], b1a[j], accp[i][j]);
                    accs[i][j] = fmaf(a2a[i], b1a[j], accs[i][j]);
                }
        }
    }
    __syncthreads();   // main-loop LDS dead; reuse for epilogue

    const float sc = scale[h];
    const float of = offs[h];

    #pragma unroll
    for (int i = 0; i < 4; ++i) {
        int r = ty * 4 + i;
        size_t grow = (size_t)row0 + r;
        float qpv[4], kpv[4];
        float s2 = 0.f;
        #pragma unroll
        for (int j = 0; j < 4; ++j) {
            float qp = sc * accp[i][j];
            float sp = accs[i][j];
            qpv[j] = qp;
            kpv[j] = fmaf(of * sc, sp, qp);
            s2 = fmaf(sp, sp, s2);
        }
        *reinterpret_cast<float4*>(&value[(grow * NH + h) * DHD + tx * 4]) =
            make_float4(accv[i][0], accv[i][1], accv[i][2], accv[i][3]);
        *reinterpret_cast<float4*>(&lds[r * 68 + tx * 4]) =
            make_float4(qpv[0], qpv[1], qpv[2], qpv[3]);
        *reinterpret_cast<float4*>(&lds[4352 + r * 68 + tx * 4]) =
            make_float4(kpv[0], kpv[1], kpv[2], kpv[3]);
        // row norm of slope_proj: reduce over the 16 tx lanes
        #pragma unroll
        for (int off = 1; off < 16; off <<= 1) s2 += __shfl_xor(s2, off, 64);
        if (tx == 0) norms[grow * NH + h] = sqrtf(s2) * (1.0f / NSEQ);
    }
    // projection matrix -> lds[8704 + m*68 + d]
    #pragma unroll
    for (int li = 0; li < 8; ++li) {
        int i = li * 256 + tid;                // 0..2047
        int m = i >> 4, cq = i & 15;
        *reinterpret_cast<float4*>(&lds[8704 + m * 68 + cq * 4]) =
            ldg4(&proj[m * DHD + cq * 4]);
    }
    __syncthreads();

    const float dnc   = 0.35355339059327373f;   // 64^-0.25
    const float ratio = 0.08838834764831845f;   // 1/sqrt(128)
    const int rhalf = tid >> 7;                 // 0/1
    const int mm = tid & 127;
    for (int pass = 0; pass < 32; ++pass) {
        int rl = pass * 2 + rhalf;
        const float* qrow = &lds[rl * 68];
        const float* krow = &lds[4352 + rl * 68];
        const float* prow = &lds[8704 + mm * 68];
        float ddq = 0.f, ddk = 0.f;
        #pragma unroll
        for (int q = 0; q < 16; ++q) {
            float4 p  = *reinterpret_cast<const float4*>(&prow[q * 4]);
            float4 qv = *reinterpret_cast<const float4*>(&qrow[q * 4]);
            float4 kv = *reinterpret_cast<const float4*>(&krow[q * 4]);
            ddq += qv.x * p.x + qv.y * p.y + qv.z * p.z + qv.w * p.w;
            ddk += kv.x * p.x + kv.y * p.y + kv.z * p.z + kv.w * p.w;
        }
        ddq *= dnc; ddk *= dnc;
        float sq, cqv, sk, ckv;
        __sincosf(ddq, &sq, &cqv);
        __sincosf(ddk, &sk, &ckv);
        size_t gbase = (((size_t)row0 + rl) * NH + h) * TWOM;
        qprime[gbase + mm]         = ratio * sq;
        qprime[gbase + MPROJ + mm] = ratio * cqv;
        kprime[gbase + mm]         = ratio * sk;
        kprime[gbase + MPROJ + mm] = ratio * ckv;
    }
}

// ---------------------------------------------------------------------------
// K2: kvs partials. grid=(16 splits, NH, B), block=256. acc 8x8/thread.
// partial[b][h][split][m(256)][d(64)]
// ---------------------------------------------------------------------------
__global__ __launch_bounds__(256, 2)
void k2_kvs_partial(const float* __restrict__ kprime, const float* __restrict__ value,
                    float* __restrict__ partial)
{
    __shared__ float kp_s[32 * 256];   // 32 KB
    __shared__ float v_s[32 * 64];     //  8 KB
    const int tid = threadIdx.x;
    const int split = blockIdx.x;
    const int h = blockIdx.y;
    const int b = blockIdx.z;
    const int tm = tid >> 3, td = tid & 7;   // m0=tm*8 (256), d0=td*8 (64)
    const int n0 = split * 256;
    float acc[8][8] = {{0.f}};
    for (int c = 0; c < 8; ++c) {
        __syncthreads();
        int nbase = n0 + c * 32;
        #pragma unroll
        for (int li = 0; li < 8; ++li) {
            int i = li * 256 + tid;          // 2048 float4
            int r = i >> 6, cq = i & 63;
            *reinterpret_cast<float4*>(&kp_s[r * 256 + cq * 4]) =
                ldg4(&kprime[(((size_t)b * NSEQ + nbase + r) * NH + h) * TWOM + cq * 4]);
        }
        #pragma unroll
        for (int li = 0; li < 2; ++li) {
            int i = li * 256 + tid;          // 512 float4
            int r = i >> 4, cq = i & 15;
            *reinterpret_cast<float4*>(&v_s[r * 64 + cq * 4]) =
                ldg4(&value[(((size_t)b * NSEQ + nbase + r) * NH + h) * DHD + cq * 4]);
        }
        __syncthreads();
        #pragma unroll 4
        for (int r = 0; r < 32; ++r) {
            float4 ka = *reinterpret_cast<const float4*>(&kp_s[r * 256 + tm * 8]);
            float4 kb = *reinterpret_cast<const float4*>(&kp_s[r * 256 + tm * 8 + 4]);
            float4 va = *reinterpret_cast<const float4*>(&v_s[r * 64 + td * 8]);
            float4 vb = *reinterpret_cast<const float4*>(&v_s[r * 64 + td * 8 + 4]);
            float kf[8] = {ka.x, ka.y, ka.z, ka.w, kb.x, kb.y, kb.z, kb.w};
            float vf[8] = {va.x, va.y, va.z, va.w, vb.x, vb.y, vb.z, vb.w};
            #pragma unroll
            for (int i = 0; i < 8; ++i)
                #pragma unroll
                for (int j = 0; j < 8; ++j)
                    acc[i][j] = fmaf(kf[i], vf[j], acc[i][j]);
        }
    }
    size_t base = (((size_t)b * NH + h) * 16 + split) * (TWOM * DHD);
    #pragma unroll
    for (int i = 0; i < 8; ++i) {
        int m = tm * 8 + i;
        *reinterpret_cast<float4*>(&partial[base + m * DHD + td * 8]) =
            make_float4(acc[i][0], acc[i][1], acc[i][2], acc[i][3]);
        *reinterpret_cast<float4*>(&partial[base + m * DHD + td * 8 + 4]) =
            make_float4(acc[i][4], acc[i][5], acc[i][6], acc[i][7]);
    }
}

// ---------------------------------------------------------------------------
// K2b: reduce 16 partials -> kvs[b][h][m][d]. grid=512, block=256.
// ---------------------------------------------------------------------------
__global__ __launch_bounds__(256)
void k2b_reduce(const float* __restrict__ partial, float* __restrict__ kvs)
{
    int idx = blockIdx.x * 256 + threadIdx.x;   // over 131072 float4
    if (idx >= (NBATCH * NH) * (TWOM * DHD / 4)) return;
    const float4* p = reinterpret_cast<const float4*>(partial);
    int bh = idx >> 12;
    int rem = idx & 4095;
    float4 s = make_float4(0.f, 0.f, 0.f, 0.f);
    size_t base = (size_t)bh * 16 * 4096 + rem;
    #pragma unroll
    for (int x = 0; x < 16; ++x) {
        float4 v = p[base + (size_t)x * 4096];
        s.x += v.x; s.y += v.y; s.z += v.z; s.w += v.w;
    }
    reinterpret_cast<float4*>(kvs)[idx] = s;
}

// ---------------------------------------------------------------------------
// K3: av = q' @ kvs (K=256), * norms. grid=(N/128, NH, B), block=256. 8x4/thr.
// ---------------------------------------------------------------------------
__global__ __launch_bounds__(256, 2)
void k3_av(const float* __restrict__ qprime, const float* __restrict__ kvs,
           const float* __restrict__ norms, float* __restrict__ av)
{
    __shared__ float A_t[32 * 132];
    __shared__ float Bs[32 * 68];
    const int tid = threadIdx.x;
    const int n0 = blockIdx.x * 128;
    const int h = blockIdx.y;
    const int b = blockIdx.z;
    const int tx = tid & 15, ty = tid >> 4;
    float acc[8][4] = {{0.f}};
    for (int k0 = 0; k0 < TWOM; k0 += 32) {
        __syncthreads();
        #pragma unroll
        for (int li = 0; li < 4; ++li) {
            int i = li * 256 + tid;          // 1024 float4
            int r = i >> 3, cq = i & 7;
            float4 v = ldg4(&qprime[(((size_t)b * NSEQ + n0 + r) * NH + h) * TWOM + k0 + cq * 4]);
            float* base = &A_t[cq * 4 * 132 + r];
            base[0] = v.x; base[132] = v.y; base[264] = v.z; base[396] = v.w;
        }
        #pragma unroll
        for (int li = 0; li < 2; ++li) {
            int i = li * 256 + tid;          // 512 float4
            int kk = i >> 4, cq = i & 15;
            *reinterpret_cast<float4*>(&Bs[kk * 68 + cq * 4]) =
                ldg4(&kvs[(((size_t)b * NH + h) * TWOM + k0 + kk) * DHD + cq * 4]);
        }
        __syncthreads();
        #pragma unroll 8
        for (int kk = 0; kk < 32; ++kk) {
            float4 a0 = *reinterpret_cast<const float4*>(&A_t[kk * 132 + ty * 8]);
            float4 a1 = *reinterpret_cast<const float4*>(&A_t[kk * 132 + ty * 8 + 4]);
            float4 bv = *reinterpret_cast<const float4*>(&Bs[kk * 68 + tx * 4]);
            float aa[8] = {a0.x, a0.y, a0.z, a0.w, a1.x, a1.y, a1.z, a1.w};
            float bb[4] = {bv.x, bv.y, bv.z, bv.w};
            #pragma unroll
            for (int i = 0; i < 8; ++i)
                #pragma unroll
                for (int j = 0; j < 4; ++j)
                    acc[i][j] = fmaf(aa[i], bb[j], acc[i][j]);
        }
    }
    #pragma unroll
    for (int i = 0; i < 8; ++i) {
        int r = ty * 8 + i;
        size_t grow = (size_t)b * NSEQ + n0 + r;
        float nm = norms[grow * NH + h];
        *reinterpret_cast<float4*>(&av[(grow * NH + h) * DHD + tx * 4]) =
            make_float4(acc[i][0] * nm, acc[i][1] * nm, acc[i][2] * nm, acc[i][3] * nm);
    }
}

// ---------------------------------------------------------------------------
// K4: out = av @ output_weight (K=512). grid=(D/64, BN/128), block=256.
// ---------------------------------------------------------------------------
__global__ __launch_bounds__(256, 2)
void k4_out(const float* __restrict__ av, const float* __restrict__ ow,
            float* __restrict__ out)
{
    __shared__ float A_t[32 * 132];
    __shared__ float Bs[32 * 68];
    const int tid = threadIdx.x;
    const int c0 = blockIdx.x * 64;
    const int row0 = blockIdx.y * 128;
    const int tx = tid & 15, ty = tid >> 4;
    float acc[8][4] = {{0.f}};
    for (int k0 = 0; k0 < DMODEL; k0 += 32) {
        __syncthreads();
        #pragma unroll
        for (int li = 0; li < 4; ++li) {
            int i = li * 256 + tid;
            int r = i >> 3, cq = i & 7;
            float4 v = ldg4(&av[(size_t)(row0 + r) * DMODEL + k0 + cq * 4]);
            float* base = &A_t[cq * 4 * 132 + r];
            base[0] = v.x; base[132] = v.y; base[264] = v.z; base[396] = v.w;
        }
        #pragma unroll
        for (int li = 0; li < 2; ++li) {
            int i = li * 256 + tid;
            int kk = i >> 4, cq = i & 15;
            *reinterpret_cast<float4*>(&Bs[kk * 68 + cq * 4]) =
                ldg4(&ow[(size_t)(k0 + kk) * DMODEL + c0 + cq * 4]);
        }
        __syncthreads();
        #pragma unroll 8
        for (int kk = 0; kk < 32; ++kk) {
            float4 a0 = *reinterpret_cast<const float4*>(&A_t[kk * 132 + ty * 8]);
            float4 a1 = *reinterpret_cast<const float4*>(&A_t[kk * 132 + ty * 8 + 4]);
            float4 bv = *reinterpret_cast<const float4*>(&Bs[kk * 68 + tx * 4]);
            float aa[8] = {a0.x, a0.y, a0.z, a0.w, a1.x, a1.y, a1.z, a1.w};
            float bb[4] = {bv.x, bv.y, bv.z, bv.w};
            #pragma unroll
            for (int i = 0; i < 8; ++i)
                #pragma unroll
                for (int j = 0; j < 4; ++j)
                    acc[i][j] = fmaf(aa[i], bb[j], acc[i][j]);
        }
    }
    #pragma unroll
    for (int i = 0; i < 8; ++i) {
        int r = row0 + ty * 8 + i;
        *reinterpret_cast<float4*>(&out[(size_t)r * DMODEL + c0 + tx * 4]) =
            make_float4(acc[i][0], acc[i][1], acc[i][2], acc[i][3]);
    }
}

// ---------------------------------------------------------------------------
extern "C" void kernel_launch(void* const* d_in, const int* in_sizes, int n_in,
                              void* d_out, int out_size, void* d_ws, size_t ws_size,
                              hipStream_t stream) {
    (void)in_sizes; (void)n_in; (void)out_size; (void)ws_size;
    const float* src   = (const float*)d_in[0];   // source_input [B,N,D]
    const float* pos   = (const float*)d_in[1];   // pos_ft
    const float* slo   = (const float*)d_in[2];   // pos_ft_slopes
    const float* vw    = (const float*)d_in[3];   // value_weight [D,H,DH]
    const float* pw    = (const float*)d_in[4];   // pos_ft_weight
    const float* scale = (const float*)d_in[5];   // [H]
    const float* offs  = (const float*)d_in[6];   // [H]
    const float* ow    = (const float*)d_in[7];   // output_weight [512,512]
    const float* proj  = (const float*)d_in[8];   // [128,64]

    float* out    = (float*)d_out;                // [B,N,D]        8388608
    float* qprime = out + 8388608;                // [B,N,H,256]   33554432
    float* kprime = out + 41943040;               // [B,N,H,256]   33554432

    // workspace: 17,432,576 floats = 66.5 MB
    float* ws      = (float*)d_ws;
    float* value   = ws;                          // 8388608  [B,N,H,DH]
    float* av_part = ws + 8388608;                // 8388608  partial, then av
    float* norms   = ws + 16777216;               // 131072   [B,N,H]
    float* kvs     = ws + 16908288;               // 524288   [B,H,256,64]

    k1_proj_ff<<<dim3(NH, BN_TOT / 64), 256, 0, stream>>>(
        src, pos, slo, vw, pw, scale, offs, proj, value, norms, qprime, kprime);
    k2_kvs_partial<<<dim3(16, NH, NBATCH), 256, 0, stream>>>(kprime, value, av_part);
    k2b_reduce<<<dim3(512), 256, 0, stream>>>(av_part, kvs);
    k3_av<<<dim3(NSEQ / 128, NH, NBATCH), 256, 0, stream>>>(qprime, kvs, norms, av_part);
    k4_out<<<dim3(DMODEL / 64, BN_TOT / 128), 256, 0, stream>>>(av_part, ow, out);
}